// Round 3
// baseline (369.644 us; speedup 1.0000x reference)
//
#include <hip/hip_runtime.h>

// Problem constants (match reference)
constexpr int NB = 16384;   // B
constexpr int NK = 50;      // K
constexpr int NH = 64;      // H
constexpr float REG = 0.01f;
constexpr int NGRP = 13;    // ceil(NK/4) row-groups (quarter-wave = one row)
constexpr int G = 4;        // b's per wave, software-pipelined

// acc[0] = sum (pred-target)^2 over B*K
// acc[1] = sum ||ue||          over B
// acc[2] = sum ||ie||          over B*K
//
// Single-buffer group-granular pipeline, LDS-free:
//  - 13 quarter-wave dwordx4 loads per b (fully-coalesced 256B row gathers),
//    saddr + 32-bit voffset form (table is 256MB, offsets fit u32).
//  - ONE float4[13] row buffer: consume r[gr] of b, then immediately re-issue
//    group gr of b+1 into the same registers. Issue order == consume order, so
//    the compiler's vmcnt waits keep ~12 loads outstanding in steady state --
//    round-2's MLP at HALF the row registers (52 vs 104 VGPR).
//  - VGPR ~115 -> __launch_bounds__(256,4): 16 waves/CU (was 12). Grid = 1024
//    blocks = 4 blocks/CU -> entire grid co-resident, no dispatch rounds.
//  - index loads 3 b's ahead, dependent bias/ue loads 2 b's ahead, both issued
//    at the TOP of each consume so they have ~1000 cyc to land.
//  - item bias folded analytically: pred = dot(ie,ue) + ib*sum(ue);
//    ||ie+ib||^2 = sum(ie^2) + 2*ib*sum(ie) + 64*ib^2.
//  - consume is pure VALU: FMAs + 16-lane DPP tree reductions (no LDS pipe).

template<int CTRL>
__device__ __forceinline__ float dpp_movf(float x) {
    return __int_as_float(__builtin_amdgcn_update_dpp(
        0, __float_as_int(x), CTRL, 0xF, 0xF, true));
}

// Sum across each 16-lane row; all 16 lanes end with the total. Pure VALU.
__device__ __forceinline__ float row16_sum(float x) {
    x += dpp_movf<0xB1>(x);    // quad_perm [1,0,3,2]  (xor 1)
    x += dpp_movf<0x4E>(x);    // quad_perm [2,3,0,1]  (xor 2)
    x += dpp_movf<0x124>(x);   // row_ror:4
    x += dpp_movf<0x128>(x);   // row_ror:8
    return x;
}

__global__ __launch_bounds__(256, 4) void mf_main(
    const float* __restrict__ user_weight,   // [NU, H]
    const float* __restrict__ item_weight,   // [NI, H]
    const float* __restrict__ user_bias,     // [NU, 1]
    const float* __restrict__ item_bias,     // [NI, 1]
    const float* __restrict__ gbias,         // [1]
    const float* __restrict__ target,        // [B, K]
    const int*   __restrict__ user,          // [B]
    const int*   __restrict__ item,          // [B, K]
    float* __restrict__ out,                 // [B*K + 1]
    float* __restrict__ acc)                 // [3] zeroed
{
    const int tid  = threadIdx.x;
    const int wave = tid >> 6;
    const int lane = tid & 63;
    const int q    = lane >> 4;   // quarter id: which row of the group of 4
    const int l16  = lane & 15;   // float4 chunk within a 256B row
    const bool active = (lane < NK);
    const int kcl  = active ? lane : (NK - 1);
    const int srcl = ((kcl & 3) << 4) + (kcl >> 2);  // lane holding row k's sums
    const int coff = l16 << 2;                       // element offset of chunk

    __shared__ float s_red[3][4];

    const int b0 = (blockIdx.x * 4 + wave) * G;
    const float gb = gbias[0];

    float4 r[NGRP];
    float mse_acc = 0.f, ien_acc = 0.f, uen_acc = 0.f;

    // rotating operand slots (all indices compile-time after full unroll)
    int   u_[3], kx_[3];
    float tg_[3];
    float ub_[2], ib_[2];
    float4 uv_[2];

    auto ld_idx = [&](int bb, int& U, int& KX, float& TG) {
        U  = user[bb];
        KX = item[bb * NK + kcl];
        TG = target[bb * NK + kcl];
    };
    auto ld_dep = [&](int U, int KX, float& UB, float& IB, float4& UV) {
        UB = user_bias[U];
        IB = item_bias[KX];
        UV = *reinterpret_cast<const float4*>(
                 user_weight + (uint32_t)(U * NH + coff));   // saddr + u32 voffset
    };
    auto gath1 = [&](int gr, int KX) -> float4 {
        const int k  = gr * 4 + q;
        const int kk = (k < NK) ? k : (NK - 1);
        const int it = __shfl(KX, kk);
        return *reinterpret_cast<const float4*>(
                   item_weight + (uint32_t)(it * NH + coff)); // saddr + u32 voffset
    };

    // ---- prologue: fill the pipeline ----
    ld_idx(b0 + 0, u_[0], kx_[0], tg_[0]);
    ld_dep(u_[0], kx_[0], ub_[0], ib_[0], uv_[0]);
    #pragma unroll
    for (int gr = 0; gr < NGRP; ++gr) r[gr] = gath1(gr, kx_[0]);
    ld_idx(b0 + 1, u_[1], kx_[1], tg_[1]);
    ld_dep(u_[1], kx_[1], ub_[1], ib_[1], uv_[1]);
    ld_idx(b0 + 2, u_[2], kx_[2], tg_[2]);

    // ---- main: fully unrolled, group-granular re-issue ----
    #pragma unroll
    for (int g = 0; g < G; ++g) {
        // copy this b's operands to locals (slots get recycled below)
        const float UB = ub_[g & 1], IB = ib_[g & 1], TG = tg_[g % 3];
        const float4 UV = uv_[g & 1];

        // prefetch deps for b+2 into the slot just copied out
        if (g + 2 < G) ld_dep(u_[(g + 2) % 3], kx_[(g + 2) % 3],
                              ub_[g & 1], ib_[g & 1], uv_[g & 1]);
        // prefetch indices for b+3 into the index slot just copied out
        if (g + 3 < G) ld_idx(b0 + g + 3, u_[g % 3], kx_[g % 3], tg_[g % 3]);

        // build ue for this b
        float4 ue = UV;
        ue.x += UB; ue.y += UB; ue.z += UB; ue.w += UB;
        float us = ue.x * ue.x + ue.y * ue.y + ue.z * ue.z + ue.w * ue.w;
        float su = ue.x + ue.y + ue.z + ue.w;
        us = row16_sum(us);
        su = row16_sum(su);
        if (lane == 0) uen_acc += sqrtf(us);

        const int KXN = kx_[(g + 1) % 3];   // rows to re-issue (b+1)
        float kd = 0.f, ks = 0.f, kp = 0.f;
        #pragma unroll
        for (int gr = 0; gr < NGRP; ++gr) {
            const float4 iv = r[gr];
            if (g + 1 < G) r[gr] = gath1(gr, KXN);   // WAR: issue right after read
            float pd = iv.x * ue.x + iv.y * ue.y + iv.z * ue.z + iv.w * ue.w;
            float ps = iv.x * iv.x + iv.y * iv.y + iv.z * iv.z + iv.w * iv.w;
            float pp = iv.x + iv.y + iv.z + iv.w;
            pd = row16_sum(pd);
            ps = row16_sum(ps);
            pp = row16_sum(pp);
            if (l16 == gr) { kd = pd; ks = ps; kp = pp; }
        }

        // route row k's sums to lane k
        const float dot = __shfl(kd, srcl);
        const float sq0 = __shfl(ks, srcl);
        const float sm  = __shfl(kp, srcl);
        if (active) {
            const float pred = dot + IB * su + gb;
            out[(b0 + g) * NK + lane] = pred;        // coalesced 200B store
            const float d = pred - TG;
            mse_acc += d * d;
            const float sq = sq0 + 2.f * IB * sm + 64.f * IB * IB;
            ien_acc += sqrtf(sq);
        }
    }

    // ---- one wave reduction at the end ----
    #pragma unroll
    for (int off = 32; off > 0; off >>= 1) {
        mse_acc += __shfl_down(mse_acc, off);
        ien_acc += __shfl_down(ien_acc, off);
    }
    if (lane == 0) {
        s_red[0][wave] = mse_acc;
        s_red[1][wave] = uen_acc;
        s_red[2][wave] = ien_acc;
    }
    __syncthreads();
    if (tid == 0) {
        atomicAdd(&acc[0], s_red[0][0] + s_red[0][1] + s_red[0][2] + s_red[0][3]);
        atomicAdd(&acc[1], s_red[1][0] + s_red[1][1] + s_red[1][2] + s_red[1][3]);
        atomicAdd(&acc[2], s_red[2][0] + s_red[2][1] + s_red[2][2] + s_red[2][3]);
    }
}

__global__ void mf_finish(const float* __restrict__ acc, float* __restrict__ out)
{
    const float inv_bk = 1.0f / (float)(NB * NK);
    const float mse = acc[0] * inv_bk;
    const float loss = mse + REG * (acc[1] / (float)NB) + REG * (acc[2] * inv_bk);
    out[NB * NK] = loss;
}

extern "C" void kernel_launch(void* const* d_in, const int* in_sizes, int n_in,
                              void* d_out, int out_size, void* d_ws, size_t ws_size,
                              hipStream_t stream) {
    const float* user_weight = (const float*)d_in[0];
    const float* item_weight = (const float*)d_in[1];
    const float* user_bias   = (const float*)d_in[2];
    const float* item_bias   = (const float*)d_in[3];
    const float* gbias       = (const float*)d_in[4];
    const float* target      = (const float*)d_in[5];
    const int*   user        = (const int*)d_in[6];
    const int*   item        = (const int*)d_in[7];
    float* out = (float*)d_out;
    float* acc = (float*)d_ws;

    hipMemsetAsync(acc, 0, 3 * sizeof(float), stream);
    mf_main<<<NB / (4 * G), 256, 0, stream>>>(user_weight, item_weight, user_bias, item_bias,
                                              gbias, target, user, item, out, acc);
    mf_finish<<<1, 1, 0, stream>>>(acc, out);
}